// Round 1
// baseline (112.856 us; speedup 1.0000x reference)
//
#include <hip/hip_runtime.h>

// Dense image warp (bilinear, tfa interpolate_bilinear semantics)
// x:    [B, H, W, C] fp32
// flow: [B, H, W, 2] fp32
// out:  [B, H, W, C] fp32
//
// B=4, H=512, W=512, C=64. Each pixel is handled by 16 lanes, each lane
// owning a float4 channel chunk (64 channels = 16 * float4). Lanes within a
// pixel are consecutive -> each corner read is a contiguous 256B burst.

constexpr int BD = 4;
constexpr int HD = 512;
constexpr int WD = 512;
constexpr int CD = 64;

__global__ __launch_bounds__(256) void warp_bilinear_kernel(
    const float* __restrict__ x,
    const float* __restrict__ flow,
    float* __restrict__ out)
{
    const int gtid = blockIdx.x * 256 + threadIdx.x;
    const int p    = gtid >> 4;          // pixel index in [0, B*H*W)
    const int lane = gtid & 15;          // which float4 channel chunk
    const int c4   = lane << 2;          // channel offset 0..60

    // p = ((b*H + h)*W + w)
    const int w  = p & (WD - 1);
    const int hb = p >> 9;               // p / W  (W=512)
    const int h  = hb & (HD - 1);
    const int b  = hb >> 9;              // hb / H (H=512)

    const float2 fl = reinterpret_cast<const float2*>(flow)[p];
    const float qx = (float)w + fl.x;
    const float qy = (float)h + fl.y;

    // tfa: floor clamped to [0, size-2], alpha clamped to [0, 1]
    float fxf = fminf(fmaxf(floorf(qx), 0.0f), (float)(WD - 2));
    float fyf = fminf(fmaxf(floorf(qy), 0.0f), (float)(HD - 2));
    const float ax = fminf(fmaxf(qx - fxf, 0.0f), 1.0f);
    const float ay = fminf(fmaxf(qy - fyf, 0.0f), 1.0f);
    const int fx = (int)fxf;
    const int fy = (int)fyf;

    const size_t base_idx = ((((size_t)b * HD + fy) * WD + fx) * CD) + c4;
    const float* base = x + base_idx;

    const float4 tl = *reinterpret_cast<const float4*>(base);
    const float4 tr = *reinterpret_cast<const float4*>(base + CD);
    const float4 bl = *reinterpret_cast<const float4*>(base + (size_t)WD * CD);
    const float4 br = *reinterpret_cast<const float4*>(base + (size_t)WD * CD + CD);

    float4 o;
    {
        float it = fmaf(ax, tr.x - tl.x, tl.x);
        float ib = fmaf(ax, br.x - bl.x, bl.x);
        o.x = fmaf(ay, ib - it, it);
    }
    {
        float it = fmaf(ax, tr.y - tl.y, tl.y);
        float ib = fmaf(ax, br.y - bl.y, bl.y);
        o.y = fmaf(ay, ib - it, it);
    }
    {
        float it = fmaf(ax, tr.z - tl.z, tl.z);
        float ib = fmaf(ax, br.z - bl.z, bl.z);
        o.z = fmaf(ay, ib - it, it);
    }
    {
        float it = fmaf(ax, tr.w - tl.w, tl.w);
        float ib = fmaf(ax, br.w - bl.w, bl.w);
        o.w = fmaf(ay, ib - it, it);
    }

    reinterpret_cast<float4*>(out)[(size_t)p * 16 + lane] = o;
}

extern "C" void kernel_launch(void* const* d_in, const int* in_sizes, int n_in,
                              void* d_out, int out_size, void* d_ws, size_t ws_size,
                              hipStream_t stream) {
    const float* x    = (const float*)d_in[0];
    const float* flow = (const float*)d_in[1];
    float* out        = (float*)d_out;

    // total lanes = B*H*W * 16 = 16,777,216 -> 65,536 blocks of 256
    const int total_threads = BD * HD * WD * 16;
    const int blocks = total_threads / 256;
    warp_bilinear_kernel<<<blocks, 256, 0, stream>>>(x, flow, out);
}

// Round 3
// 99.850 us; speedup vs baseline: 1.1303x; 1.1303x over previous
//
#include <hip/hip_runtime.h>

// Dense image warp (bilinear, tfa interpolate_bilinear semantics)
// x:    [B, H, W, C] fp32
// flow: [B, H, W, 2] fp32
// out:  [B, H, W, C] fp32
//
// B=4, H=512, W=512, C=64. Each pixel handled by 16 lanes, each lane owning a
// float4 channel chunk. R3 = R2 with native ext_vector types so the
// nontemporal builtins compile:
//  - XCD-aware block swizzle: each of the 8 XCDs gets a contiguous slab of
//    the image so shared corner cache lines stay in ONE private L2 and the
//    reuse window (~8 rows ~ 1 MB) fits in the 4 MiB per-XCD L2.
//  - Non-temporal store for `out` and nt load for `flow` (write-once /
//    read-once streams must not evict x's reusable corner lines from L2).

typedef float f32x4 __attribute__((ext_vector_type(4)));
typedef float f32x2 __attribute__((ext_vector_type(2)));

constexpr int BD = 4;
constexpr int HD = 512;
constexpr int WD = 512;
constexpr int CD = 64;
constexpr int NBLOCKS = BD * HD * WD * 16 / 256;  // 65536
constexpr int NXCD = 8;
constexpr int CHUNK = NBLOCKS / NXCD;             // 8192 (exact)

__global__ __launch_bounds__(256) void warp_bilinear_kernel(
    const float* __restrict__ x,
    const float* __restrict__ flow,
    float* __restrict__ out)
{
    // XCD swizzle: default dispatch round-robins blockIdx.x across XCDs.
    // Remap so XCD k executes blocks [k*CHUNK, (k+1)*CHUNK) — a contiguous
    // half-image slab per XCD. NBLOCKS % 8 == 0 so this is bijective.
    const int bid = (blockIdx.x % NXCD) * CHUNK + (blockIdx.x / NXCD);

    const int gtid = bid * 256 + threadIdx.x;
    const int p    = gtid >> 4;          // pixel index in [0, B*H*W)
    const int lane = gtid & 15;          // which float4 channel chunk
    const int c4   = lane << 2;          // channel offset 0..60

    // p = ((b*H + h)*W + w)
    const int w  = p & (WD - 1);
    const int hb = p >> 9;               // p / W  (W=512)
    const int h  = hb & (HD - 1);
    const int b  = hb >> 9;              // hb / H (H=512)

    const f32x2 fl =
        __builtin_nontemporal_load(reinterpret_cast<const f32x2*>(flow) + p);
    const float qx = (float)w + fl.x;
    const float qy = (float)h + fl.y;

    // tfa: floor clamped to [0, size-2], alpha clamped to [0, 1]
    float fxf = fminf(fmaxf(floorf(qx), 0.0f), (float)(WD - 2));
    float fyf = fminf(fmaxf(floorf(qy), 0.0f), (float)(HD - 2));
    const float ax = fminf(fmaxf(qx - fxf, 0.0f), 1.0f);
    const float ay = fminf(fmaxf(qy - fyf, 0.0f), 1.0f);
    const int fx = (int)fxf;
    const int fy = (int)fyf;

    const size_t base_idx = ((((size_t)b * HD + fy) * WD + fx) * CD) + c4;
    const float* base = x + base_idx;

    const f32x4 tl = *reinterpret_cast<const f32x4*>(base);
    const f32x4 tr = *reinterpret_cast<const f32x4*>(base + CD);
    const f32x4 bl = *reinterpret_cast<const f32x4*>(base + (size_t)WD * CD);
    const f32x4 br = *reinterpret_cast<const f32x4*>(base + (size_t)WD * CD + CD);

    // it = ax*(tr-tl)+tl ; ib = ax*(br-bl)+bl ; o = ay*(ib-it)+it  (vectorized)
    f32x4 it = (tr - tl) * ax + tl;
    f32x4 ib = (br - bl) * ax + bl;
    f32x4 o  = (ib - it) * ay + it;

    __builtin_nontemporal_store(
        o, reinterpret_cast<f32x4*>(out) + (size_t)p * 16 + lane);
}

extern "C" void kernel_launch(void* const* d_in, const int* in_sizes, int n_in,
                              void* d_out, int out_size, void* d_ws, size_t ws_size,
                              hipStream_t stream) {
    const float* x    = (const float*)d_in[0];
    const float* flow = (const float*)d_in[1];
    float* out        = (float*)d_out;

    warp_bilinear_kernel<<<NBLOCKS, 256, 0, stream>>>(x, flow, out);
}

// Round 4
// 97.026 us; speedup vs baseline: 1.1631x; 1.0291x over previous
//
#include <hip/hip_runtime.h>

// Dense image warp (bilinear, tfa interpolate_bilinear semantics)
// x:    [B, H, W, C] fp32   (B=4, H=512, W=512, C=64)
// flow: [B, H, W, 2] fp32
// out:  [B, H, W, C] fp32
//
// R4: 8 lanes per pixel, each lane owns TWO float4 channel chunks
// (c = sub*4 and sub*4+32). vs R3 (16 lanes/px):
//  - halves the redundant per-pixel scalar VALU (index decode, clamp,
//    address chain) — was ~57 VALU instrs per wave for only 4 pixels
//  - doubles per-thread MLP: 8 independent gather loads in flight
//  - memory pattern unchanged: each corner chunk load is a 128 B
//    contiguous line per 8-lane group; stores fully coalesced.
// Keeps R3's XCD slab swizzle + nt flow load + nt out store.

typedef float f32x4 __attribute__((ext_vector_type(4)));
typedef float f32x2 __attribute__((ext_vector_type(2)));

constexpr int BD = 4;
constexpr int HD = 512;
constexpr int WD = 512;
constexpr int CD = 64;
constexpr int NBLOCKS = BD * HD * WD * 8 / 256;   // 32768
constexpr int NXCD = 8;
constexpr int CHUNK = NBLOCKS / NXCD;             // 4096 (exact)

__global__ __launch_bounds__(256) void warp_bilinear_kernel(
    const float* __restrict__ x,
    const float* __restrict__ flow,
    float* __restrict__ out)
{
    // XCD swizzle: each XCD gets a contiguous slab of the image.
    const int bid = (blockIdx.x & (NXCD - 1)) * CHUNK + (blockIdx.x >> 3);

    const int gtid = bid * 256 + threadIdx.x;
    const int p    = gtid >> 3;          // pixel index in [0, B*H*W)
    const int sub  = gtid & 7;           // lane within pixel
    const int c0   = sub << 2;           // channels c0..c0+3 and c0+32..c0+35

    // p = ((b*H + h)*W + w)
    const int w  = p & (WD - 1);
    const int hb = p >> 9;               // p / W
    const int h  = hb & (HD - 1);
    const int b  = hb >> 9;              // hb / H

    const f32x2 fl =
        __builtin_nontemporal_load(reinterpret_cast<const f32x2*>(flow) + p);
    const float qx = (float)w + fl.x;
    const float qy = (float)h + fl.y;

    // tfa: floor clamped to [0, size-2], alpha clamped to [0, 1]
    float fxf = fminf(fmaxf(floorf(qx), 0.0f), (float)(WD - 2));
    float fyf = fminf(fmaxf(floorf(qy), 0.0f), (float)(HD - 2));
    const float ax = fminf(fmaxf(qx - fxf, 0.0f), 1.0f);
    const float ay = fminf(fmaxf(qy - fyf, 0.0f), 1.0f);
    const int fx = (int)fxf;
    const int fy = (int)fyf;

    const size_t base_idx = ((((size_t)b * HD + fy) * WD + fx) * CD) + c0;
    const float* base = x + base_idx;
    const float* baseb = base + (size_t)WD * CD;   // row fy+1

    // 8 independent gather loads (max MLP), then compute.
    const f32x4 tl0 = *reinterpret_cast<const f32x4*>(base);
    const f32x4 tl1 = *reinterpret_cast<const f32x4*>(base + 32);
    const f32x4 tr0 = *reinterpret_cast<const f32x4*>(base + CD);
    const f32x4 tr1 = *reinterpret_cast<const f32x4*>(base + CD + 32);
    const f32x4 bl0 = *reinterpret_cast<const f32x4*>(baseb);
    const f32x4 bl1 = *reinterpret_cast<const f32x4*>(baseb + 32);
    const f32x4 br0 = *reinterpret_cast<const f32x4*>(baseb + CD);
    const f32x4 br1 = *reinterpret_cast<const f32x4*>(baseb + CD + 32);

    f32x4 it0 = (tr0 - tl0) * ax + tl0;
    f32x4 ib0 = (br0 - bl0) * ax + bl0;
    f32x4 o0  = (ib0 - it0) * ay + it0;

    f32x4 it1 = (tr1 - tl1) * ax + tl1;
    f32x4 ib1 = (br1 - bl1) * ax + bl1;
    f32x4 o1  = (ib1 - it1) * ay + it1;

    f32x4* op = reinterpret_cast<f32x4*>(out + (size_t)p * CD + c0);
    __builtin_nontemporal_store(o0, op);
    __builtin_nontemporal_store(o1, op + 8);   // +32 floats
}

extern "C" void kernel_launch(void* const* d_in, const int* in_sizes, int n_in,
                              void* d_out, int out_size, void* d_ws, size_t ws_size,
                              hipStream_t stream) {
    const float* x    = (const float*)d_in[0];
    const float* flow = (const float*)d_in[1];
    float* out        = (float*)d_out;

    warp_bilinear_kernel<<<NBLOCKS, 256, 0, stream>>>(x, flow, out);
}